// Round 8
// baseline (973.310 us; speedup 1.0000x reference)
//
#include <hip/hip_runtime.h>
#include <hip/hip_bf16.h>

typedef __attribute__((ext_vector_type(4))) float  f32x4;
typedef __attribute__((ext_vector_type(8))) short  bf16x8;
typedef __attribute__((ext_vector_type(4))) int    i32x4;

#define M_DIM 8192
#define N_DIM 11008
#define K_DIM 4096
#define KP    2048

#define A_WS_BYTES ((size_t)M_DIM * K_DIM * 2)
#define B_WS_BYTES ((size_t)N_DIM * K_DIM * 2)
#define WS_NEED    (A_WS_BYTES + B_WS_BYTES)

// ---- 128x256 tile, BK=64, 8 waves (2Mx4N), 3 LDS buffers, 2-phase K-step ----
#define BM 128
#define BN 256
#define BK 64
#define NT (K_DIM / BK)          // 64 K-tiles
#define ATILE_BYTES 16384        // 128 x 64 x 2B
#define BTILE_BYTES 32768        // 256 x 64 x 2B
#define BUF_BYTES   49152        // A + B
// LDS total: 3 * 49152 = 147456 (<= 160 KiB)

__device__ __forceinline__ short f2bf(float f) {
    return __builtin_bit_cast(short, __float2bfloat16(f));
}

// ---------------- prepass: x fp32 -> bf16 ----------------
__global__ __launch_bounds__(256)
void cvt_x_kernel(const float* __restrict__ x, short* __restrict__ xb)
{
    const size_t i = ((size_t)blockIdx.x * 256 + threadIdx.x) * 8;
    const f32x4 a = *(const f32x4*)(x + i);
    const f32x4 b = *(const f32x4*)(x + i + 4);
    bf16x8 o;
    #pragma unroll
    for (int j = 0; j < 4; ++j) {
        o[j]     = f2bf(a[j]);
        o[4 + j] = f2bf(b[j]);
    }
    *(bf16x8*)(xb + i) = o;
}

// ---------------- prepass: packed int4 -> bf16 (row-major, exact ints) ----------------
__global__ __launch_bounds__(256)
void dequant_w_kernel(const int* __restrict__ wq, short* __restrict__ wb)
{
    const size_t i = ((size_t)blockIdx.x * 256 + threadIdx.x) * 4;
    const i32x4 v = *(const i32x4*)(wq + i);
    bf16x8 o;
    #pragma unroll
    for (int j = 0; j < 4; ++j) {
        const int q = (v[j] & 0xFF) ^ 0x88;
        o[2 * j]     = f2bf((float)((q & 15) - 8));
        o[2 * j + 1] = f2bf((float)(((q >> 4) & 15) - 8));
    }
    *(bf16x8*)(wb + i * 2) = o;
}

// ---------------- main GEMM: 128x256, 8-phase rhythm, 3-deep counted-vmcnt ----------------
__global__ __launch_bounds__(512, 2)
void gemm128x256_kernel(const short* __restrict__ A,     // [8192][4096] bf16
                        const short* __restrict__ Bw,    // [11008][4096] bf16
                        const float* __restrict__ scale,
                        const float* __restrict__ bias,
                        float* __restrict__ out)
{
    __shared__ char lds[3 * BUF_BYTES];   // 144 KiB

    const int t    = threadIdx.x;
    const int lane = t & 63;
    const int wv   = t >> 6;          // 0..7
    const int wm   = wv >> 2;         // 0..1 -> M half (64 rows)
    const int wn   = wv & 3;          // 0..3 -> N quarter (64 cols)

    // bijective XCD chunk swizzle (nwg = 2752 = 8*344)
    const int nbx = N_DIM / BN;                       // 43
    const int cpx = (nbx * (M_DIM / BM)) >> 3;        // 344
    const int bid = blockIdx.x;
    const int sid = (bid & 7) * cpx + (bid >> 3);
    const int by  = sid / nbx;                        // 0..63
    const int bx  = sid - by * nbx;                   // 0..42
    const int m0  = by * BM;
    const int n0  = bx * BN;

    // ---- staging: wave-chunk form (uniform base + lane*16), pre-swizzled source ----
    // chunk covers 8 rows; lane -> row chunk*8 + (lane>>3), phys granule lane&7.
    // phys granule p at row r holds logical granule p ^ (r&7); source col = ((lane&7)^(lane>>3))*8
    const int swcol = ((lane & 7) ^ (lane >> 3)) * 8;
    const short* aS[2];  int aD[2];
    const short* bS[4];  int bD[4];
    #pragma unroll
    for (int i = 0; i < 2; ++i) {
        const int c = wv * 2 + i;                              // A chunk 0..15
        aS[i] = A + (size_t)(m0 + c * 8 + (lane >> 3)) * K_DIM + swcol;
        aD[i] = c * 1024 + lane * 16;
    }
    #pragma unroll
    for (int j = 0; j < 4; ++j) {
        const int c = wv * 4 + j;                              // B chunk 0..31
        bS[j] = Bw + (size_t)(n0 + c * 8 + (lane >> 3)) * K_DIM + swcol;
        bD[j] = ATILE_BYTES + c * 1024 + lane * 16;
    }

#define GLDS(SRC, DST) __builtin_amdgcn_global_load_lds(                         \
        (const __attribute__((address_space(1))) unsigned int*)(SRC),            \
        (__attribute__((address_space(3))) unsigned int*)(lds + (DST)), 16, 0, 0)

#define STG_P1(ST, kt_) do { const int ko_ = (kt_) * BK;                         \
    GLDS(aS[0] + ko_, (ST) + aD[0]);                                             \
    GLDS(bS[0] + ko_, (ST) + bD[0]);                                             \
    GLDS(bS[1] + ko_, (ST) + bD[1]); } while (0)

#define STG_P2(ST, kt_) do { const int ko_ = (kt_) * BK;                         \
    GLDS(aS[1] + ko_, (ST) + aD[1]);                                             \
    GLDS(bS[2] + ko_, (ST) + bD[2]);                                             \
    GLDS(bS[3] + ko_, (ST) + bD[3]); } while (0)

    // ---- fragment read offsets (swizzled; ks1 = offset ^ 64) ----
    const int lr = lane & 15;
    const int lk = lane >> 4;
    int aOff[4], bOff[4];
    #pragma unroll
    for (int mi = 0; mi < 4; ++mi) {
        const int row = wm * 64 + mi * 16 + lr;
        aOff[mi] = row * 128 + ((lk ^ (row & 7)) * 16);
    }
    #pragma unroll
    for (int ni = 0; ni < 4; ++ni) {
        const int row = wn * 64 + ni * 16 + lr;
        bOff[ni] = ATILE_BYTES + row * 128 + ((lk ^ (row & 7)) * 16);
    }

    f32x4 acc[4][4];
    #pragma unroll
    for (int mi = 0; mi < 4; ++mi)
        #pragma unroll
        for (int ni = 0; ni < 4; ++ni)
            acc[mi][ni] = (f32x4){0.f, 0.f, 0.f, 0.f};

#define BAR   __builtin_amdgcn_s_barrier()
#define LGKM0 asm volatile("s_waitcnt lgkmcnt(0)" ::: "memory")
#define VMC(N) asm volatile("s_waitcnt vmcnt(" #N ")" ::: "memory")

#define PHASE(BO, KS) do {                                                       \
    bf16x8 af_[4], bf_[4];                                                       \
    _Pragma("unroll")                                                            \
    for (int m_ = 0; m_ < 4; ++m_)                                               \
        af_[m_] = *(const bf16x8*)(lds + (BO) + (aOff[m_] ^ ((KS) * 64)));       \
    _Pragma("unroll")                                                            \
    for (int n_ = 0; n_ < 4; ++n_)                                               \
        bf_[n_] = *(const bf16x8*)(lds + (BO) + (bOff[n_] ^ ((KS) * 64)));       \
    if (kt < NT - 2) { if ((KS) == 0) STG_P1(stgO, kt + 2); else STG_P2(stgO, kt + 2); } \
    BAR; LGKM0;                                                                  \
    __builtin_amdgcn_s_setprio(1);                                               \
    _Pragma("unroll")                                                            \
    for (int m_ = 0; m_ < 4; ++m_)                                               \
        _Pragma("unroll")                                                        \
        for (int n_ = 0; n_ < 4; ++n_)                                           \
            acc[m_][n_] = __builtin_amdgcn_mfma_f32_16x16x32_bf16(               \
                af_[m_], bf_[n_], acc[m_][n_], 0, 0, 0);                         \
    __builtin_amdgcn_s_setprio(0);                                               \
} while (0)

    // ---- prologue: stage tiles 0 (buf0) and 1 (buf1); drain tile 0 ----
    STG_P1(0, 0); STG_P2(0, 0);
    STG_P1(BUF_BYTES, 1); STG_P2(BUF_BYTES, 1);
    VMC(6);                       // 12 out; oldest 6 = tile0 -> resident
    BAR;

    int bufO = 0;
    int stgO = 2 * BUF_BYTES;

    for (int kt = 0; kt < NT; ++kt) {
        // phase A (ks=0): 8 ds_read | 3-load stage | bar | lgkm0 | 16 MFMA | bar
        PHASE(bufO, 0);
        BAR;
        // phase B (ks=1): 8 ds_read | 3-load stage | bar | lgkm0 | 16 MFMA
        PHASE(bufO, 1);
        // counted waits: tile kt+1 resident; tile kt+2 stays in flight
        if (kt < NT - 2)       VMC(6);
        else if (kt == NT - 2) VMC(0);
        if (kt < NT - 1) BAR;

        bufO += BUF_BYTES; if (bufO == 3 * BUF_BYTES) bufO = 0;
        stgO += BUF_BYTES; if (stgO == 3 * BUF_BYTES) stgO = 0;
    }

    // ---- epilogue: out = acc * scale[n] + bias[n] ----
    // C/D layout: col = lane&15, row = (lane>>4)*4 + reg   (verified, passing R1-R7)
    #pragma unroll
    for (int ni = 0; ni < 4; ++ni) {
        const int gn = n0 + wn * 64 + ni * 16 + lr;
        const float sc = scale[gn];
        const float bi = bias[gn];
        #pragma unroll
        for (int mi = 0; mi < 4; ++mi) {
            const int gm = m0 + wm * 64 + mi * 16 + lk * 4;
            const f32x4 v = acc[mi][ni];
            #pragma unroll
            for (int r = 0; r < 4; ++r)
                out[(size_t)(gm + r) * N_DIM + gn] = v[r] * sc + bi;
        }
    }
#undef GLDS
#undef STG_P1
#undef STG_P2
#undef PHASE
#undef BAR
#undef LGKM0
#undef VMC
}

// ---------------- fallback: fused dequant GEMM (R1 kernel, known-good) ----------------
__device__ __forceinline__ int swz(int row, int kbyte) {
    return row * 128 + (kbyte ^ ((row & 7) << 4));
}

__global__ __launch_bounds__(256, 2)
void qlin_kernel(const float* __restrict__ x,
                 const int*   __restrict__ wq,
                 const float* __restrict__ scale,
                 const float* __restrict__ bias,
                 float* __restrict__ out)
{
    __shared__ short As[128 * 64];
    __shared__ short Bs[128 * 64];

    const int t  = threadIdx.x;
    const int n0 = blockIdx.x * 128;
    const int m0 = blockIdx.y * 128;

    const int sr = t >> 1;
    const int sh = t & 1;

    const float* ag = x  + (size_t)(m0 + sr) * K_DIM + sh * 32;
    const int*   bg = wq + (size_t)(n0 + sr) * KP    + sh * 16;

    const int lane = t & 63;
    const int wv   = t >> 6;
    const int wm   = wv >> 1;
    const int wn   = wv & 1;
    const int lr   = lane & 15;
    const int lk   = lane >> 4;

    f32x4 acc[4][4];
    #pragma unroll
    for (int i = 0; i < 4; ++i)
        #pragma unroll
        for (int j = 0; j < 4; ++j)
            acc[i][j] = (f32x4){0.f, 0.f, 0.f, 0.f};

    f32x4 ar[8];
    i32x4 br[4];

    #pragma unroll
    for (int i = 0; i < 8; ++i) ar[i] = *(const f32x4*)(ag + i * 4);
    #pragma unroll
    for (int i = 0; i < 4; ++i) br[i] = *(const i32x4*)(bg + i * 4);

    for (int kt = 0; kt < 64; ++kt) {
        #pragma unroll
        for (int c = 0; c < 4; ++c) {
            bf16x8 pa;
            #pragma unroll
            for (int j = 0; j < 8; ++j)
                pa[j] = f2bf(ar[c * 2 + (j >> 2)][j & 3]);
            *(bf16x8*)((char*)As + swz(sr, sh * 64 + c * 16)) = pa;

            bf16x8 pb;
            #pragma unroll
            for (int j = 0; j < 4; ++j) {
                const int q = br[c][j] ^ 0x88;
                const float flo = __builtin_bit_cast(float, 0x4B000000 | (q & 15))        - 8388616.0f;
                const float fhi = __builtin_bit_cast(float, 0x4B000000 | ((q >> 4) & 15)) - 8388616.0f;
                pb[2 * j]     = f2bf(flo);
                pb[2 * j + 1] = f2bf(fhi);
            }
            *(bf16x8*)((char*)Bs + swz(sr, sh * 64 + c * 16)) = pb;
        }
        __syncthreads();

        if (kt + 1 < 64) {
            const float* an = ag + (kt + 1) * 64;
            const int*   bn = bg + (kt + 1) * 32;
            #pragma unroll
            for (int i = 0; i < 8; ++i) ar[i] = *(const f32x4*)(an + i * 4);
            #pragma unroll
            for (int i = 0; i < 4; ++i) br[i] = *(const i32x4*)(bn + i * 4);
        }

        #pragma unroll
        for (int ks = 0; ks < 2; ++ks) {
            const int kb = ks * 64 + lk * 16;
            bf16x8 af2[4], bf2[4];
            #pragma unroll
            for (int mi = 0; mi < 4; ++mi)
                af2[mi] = *(const bf16x8*)((const char*)As + swz(wm * 64 + mi * 16 + lr, kb));
            #pragma unroll
            for (int ni = 0; ni < 4; ++ni)
                bf2[ni] = *(const bf16x8*)((const char*)Bs + swz(wn * 64 + ni * 16 + lr, kb));
            #pragma unroll
            for (int mi = 0; mi < 4; ++mi)
                #pragma unroll
                for (int ni = 0; ni < 4; ++ni)
                    acc[mi][ni] = __builtin_amdgcn_mfma_f32_16x16x32_bf16(
                        af2[mi], bf2[ni], acc[mi][ni], 0, 0, 0);
        }
        __syncthreads();
    }

    #pragma unroll
    for (int ni = 0; ni < 4; ++ni) {
        const int gn = n0 + wn * 64 + ni * 16 + lr;
        const float sc = scale[gn];
        const float bi = bias[gn];
        #pragma unroll
        for (int mi = 0; mi < 4; ++mi) {
            const int gm = m0 + wm * 64 + mi * 16 + lk * 4;
            const f32x4 v = acc[mi][ni];
            #pragma unroll
            for (int r2 = 0; r2 < 4; ++r2)
                out[(size_t)(gm + r2) * N_DIM + gn] = v[r2] * sc + bi;
        }
    }
}

extern "C" void kernel_launch(void* const* d_in, const int* in_sizes, int n_in,
                              void* d_out, int out_size, void* d_ws, size_t ws_size,
                              hipStream_t stream)
{
    const float* x     = (const float*)d_in[0];
    const int*   wq    = (const int*)d_in[1];
    const float* scale = (const float*)d_in[2];
    const float* bias  = (const float*)d_in[3];
    float*       out   = (float*)d_out;

    if (ws_size >= WS_NEED) {
        short* xb = (short*)d_ws;
        short* wb = (short*)((char*)d_ws + A_WS_BYTES);
        cvt_x_kernel<<<16384, 256, 0, stream>>>(x, xb);
        dequant_w_kernel<<<22016, 256, 0, stream>>>(wq, wb);
        const int nwg = (N_DIM / BN) * (M_DIM / BM);   // 43*64 = 2752
        gemm128x256_kernel<<<nwg, 512, 0, stream>>>(xb, wb, scale, bias, out);
    } else {
        qlin_kernel<<<dim3(N_DIM / 128, M_DIM / 128), 256, 0, stream>>>(x, wq, scale, bias, out);
    }
}

// Round 9
// 841.220 us; speedup vs baseline: 1.1570x; 1.1570x over previous
//
#include <hip/hip_runtime.h>
#include <hip/hip_bf16.h>

typedef __attribute__((ext_vector_type(4))) float  f32x4;
typedef __attribute__((ext_vector_type(8))) short  bf16x8;
typedef __attribute__((ext_vector_type(4))) int    i32x4;

#define M_DIM 8192
#define N_DIM 11008
#define K_DIM 4096
#define KP    2048

#define A_WS_BYTES ((size_t)M_DIM * K_DIM * 2)
#define B_WS_BYTES ((size_t)N_DIM * K_DIM * 2)
#define WS_NEED    (A_WS_BYTES + B_WS_BYTES)

// ---- 256x256 tile, BK=32, 8 waves (2Mx4N), 4 LDS buffers, 2-phase K-tile ----
#define BM 256
#define BN 256
#define BK 32
#define NT (K_DIM / BK)          // 128 K-tiles
#define TILE_BYTES 32768         // A 16KB + B 16KB
// LDS total: 4 * 32768 = 131072

__device__ __forceinline__ short f2bf(float f) {
    return __builtin_bit_cast(short, __float2bfloat16(f));
}

// ---------------- prepass: x fp32 -> bf16 ----------------
__global__ __launch_bounds__(256)
void cvt_x_kernel(const float* __restrict__ x, short* __restrict__ xb)
{
    const size_t i = ((size_t)blockIdx.x * 256 + threadIdx.x) * 8;
    const f32x4 a = *(const f32x4*)(x + i);
    const f32x4 b = *(const f32x4*)(x + i + 4);
    bf16x8 o;
    #pragma unroll
    for (int j = 0; j < 4; ++j) {
        o[j]     = f2bf(a[j]);
        o[4 + j] = f2bf(b[j]);
    }
    *(bf16x8*)(xb + i) = o;
}

// ---------------- prepass: packed int4 -> bf16 (row-major, exact ints) ----------------
__global__ __launch_bounds__(256)
void dequant_w_kernel(const int* __restrict__ wq, short* __restrict__ wb)
{
    const size_t i = ((size_t)blockIdx.x * 256 + threadIdx.x) * 4;
    const i32x4 v = *(const i32x4*)(wq + i);
    bf16x8 o;
    #pragma unroll
    for (int j = 0; j < 4; ++j) {
        const int q = (v[j] & 0xFF) ^ 0x88;
        o[2 * j]     = f2bf((float)((q & 15) - 8));
        o[2 * j + 1] = f2bf((float)(((q >> 4) & 15) - 8));
    }
    *(bf16x8*)(wb + i * 2) = o;
}

// ---------------- main GEMM: 256^2, BK=32, 4-deep pipeline, 2-phase K-tile ----------------
__global__ __launch_bounds__(512, 2)
void gemm256_kernel(const short* __restrict__ A,     // [8192][4096] bf16
                    const short* __restrict__ Bw,    // [11008][4096] bf16
                    const float* __restrict__ scale,
                    const float* __restrict__ bias,
                    float* __restrict__ out)
{
    __shared__ char lds[4 * TILE_BYTES];   // 128 KiB

    const int t    = threadIdx.x;
    const int lane = t & 63;
    const int wv   = t >> 6;          // 0..7
    const int wm   = wv >> 2;         // 0..1 -> M half (128 rows)
    const int wn   = wv & 3;          // 0..3 -> N quarter (64 cols)

    // bijective XCD chunk swizzle (nwg = 1376, %8 == 0)
    const int nbx = N_DIM / BN;                       // 43
    const int cpx = (nbx * (M_DIM / BM)) >> 3;        // 172
    const int bid = blockIdx.x;
    const int sid = (bid & 7) * cpx + (bid >> 3);
    const int by  = sid / nbx;
    const int bx  = sid - by * nbx;
    const int m0  = by * BM;
    const int n0  = bx * BN;

    // ---- staging: rows of 64B (32 bf16), 4 granules of 16B per row ----
    // phys granule p at row r holds logical granule p ^ (r&3); source pre-swizzled (rule #21).
    const int srow = t >> 2;                               // 0..127
    const int lg   = (t & 3) ^ (srow & 3);                 // logical granule for this thread
    const short* aS0 = A  + (size_t)(m0 + srow)       * K_DIM + lg * 8;
    const short* aS1 = A  + (size_t)(m0 + 128 + srow) * K_DIM + lg * 8;
    const short* bS0 = Bw + (size_t)(n0 + srow)       * K_DIM + lg * 8;
    const short* bS1 = Bw + (size_t)(n0 + 128 + srow) * K_DIM + lg * 8;
    const int aD = srow * 64 + (t & 3) * 16;               // dest byte within region

#define GLDS(SRC, DST) __builtin_amdgcn_global_load_lds(                         \
        (const __attribute__((address_space(1))) unsigned int*)(SRC),            \
        (__attribute__((address_space(3))) unsigned int*)(lds + (DST)), 16, 0, 0)

#define STG_A(SB, kt_) do { const int ko_ = (kt_) * BK;                          \
    GLDS(aS0 + ko_, (SB) * TILE_BYTES + aD);                                     \
    GLDS(aS1 + ko_, (SB) * TILE_BYTES + aD + 8192); } while (0)

#define STG_B(SB, kt_) do { const int ko_ = (kt_) * BK;                          \
    GLDS(bS0 + ko_, (SB) * TILE_BYTES + 16384 + aD);                             \
    GLDS(bS1 + ko_, (SB) * TILE_BYTES + 16384 + aD + 8192); } while (0)

    // ---- fragment read offsets: row*64 + ((lk ^ (lr&3))*16); (row&3)==(lr&3) ----
    const int lr = lane & 15;
    const int lk = lane >> 4;
    int aOff[8], bOff[4];
    #pragma unroll
    for (int mi = 0; mi < 8; ++mi) {
        const int row = wm * 128 + mi * 16 + lr;
        aOff[mi] = row * 64 + ((lk ^ (lr & 3)) * 16);
    }
    #pragma unroll
    for (int ni = 0; ni < 4; ++ni) {
        const int row = wn * 64 + ni * 16 + lr;
        bOff[ni] = 16384 + row * 64 + ((lk ^ (lr & 3)) * 16);
    }

    f32x4 acc[8][4];
    #pragma unroll
    for (int mi = 0; mi < 8; ++mi)
        #pragma unroll
        for (int ni = 0; ni < 4; ++ni)
            acc[mi][ni] = (f32x4){0.f, 0.f, 0.f, 0.f};

#define BAR   __builtin_amdgcn_s_barrier()
#define LGKM0 asm volatile("s_waitcnt lgkmcnt(0)" ::: "memory")
#define VMC(N) asm volatile("s_waitcnt vmcnt(" #N ")" ::: "memory")

    // ---- prologue: stage tiles 0,1,2 into bufs 0,1,2 (12 loads); drain tile 0 ----
    STG_A(0, 0); STG_B(0, 0);
    STG_A(1, 1); STG_B(1, 1);
    STG_A(2, 2); STG_B(2, 2);
    VMC(8);                       // 12 out; oldest 4 = tile0 -> resident
    BAR;

    // ---- main loop: per K32-tile, 2 phases; stage tile kt+3 (6 phases of slack) ----
    for (int kt0 = 0; kt0 < NT; kt0 += 4) {
        #pragma unroll
        for (int u = 0; u < 4; ++u) {
            const int kt = kt0 + u;
            const char* buf = lds + u * TILE_BYTES;
            const int   sb  = (u + 3) & 3;          // == (kt+3)&3, freed by iter kt-1
            const bool  pre = (kt + 3 < NT);
            bf16x8 af_[4], bf_[4];

            // ---- phase A: 8 ds_read | stage A(kt+3) | bar | lgkm0 | 16 MFMA (m0-3) ----
            #pragma unroll
            for (int m_ = 0; m_ < 4; ++m_) af_[m_] = *(const bf16x8*)(buf + aOff[m_]);
            #pragma unroll
            for (int n_ = 0; n_ < 4; ++n_) bf_[n_] = *(const bf16x8*)(buf + bOff[n_]);
            if (pre) STG_A(sb, kt + 3);
            BAR; LGKM0;
            __builtin_amdgcn_s_setprio(1);
            #pragma unroll
            for (int m_ = 0; m_ < 4; ++m_)
                #pragma unroll
                for (int n_ = 0; n_ < 4; ++n_)
                    acc[m_][n_] = __builtin_amdgcn_mfma_f32_16x16x32_bf16(
                        af_[m_], bf_[n_], acc[m_][n_], 0, 0, 0);
            __builtin_amdgcn_s_setprio(0);
            BAR;

            // ---- phase B: 4 ds_read | stage B(kt+3) | bar | lgkm0 | 16 MFMA (m4-7) ----
            #pragma unroll
            for (int m_ = 0; m_ < 4; ++m_) af_[m_] = *(const bf16x8*)(buf + aOff[4 + m_]);
            if (pre) STG_B(sb, kt + 3);
            BAR; LGKM0;
            __builtin_amdgcn_s_setprio(1);
            #pragma unroll
            for (int m_ = 0; m_ < 4; ++m_)
                #pragma unroll
                for (int n_ = 0; n_ < 4; ++n_)
                    acc[4 + m_][n_] = __builtin_amdgcn_mfma_f32_16x16x32_bf16(
                        af_[m_], bf_[n_], acc[4 + m_][n_], 0, 0, 0);
            __builtin_amdgcn_s_setprio(0);

            // counted waits: tile kt+1 resident; tiles kt+2, kt+3 stay in flight
            if (kt < NT - 3)       VMC(8);
            else if (kt == NT - 3) VMC(4);
            else if (kt == NT - 2) VMC(0);
            if (kt < NT - 1) BAR;
        }
    }

    // ---- epilogue: out = acc * scale[n] + bias[n] ----
    // C/D layout: col = lane&15, row = (lane>>4)*4 + reg   (verified, passing R1-R8)
    #pragma unroll
    for (int ni = 0; ni < 4; ++ni) {
        const int gn = n0 + wn * 64 + ni * 16 + lr;
        const float sc = scale[gn];
        const float bi = bias[gn];
        #pragma unroll
        for (int mi = 0; mi < 8; ++mi) {
            const int gm = m0 + wm * 128 + mi * 16 + lk * 4;
            const f32x4 v = acc[mi][ni];
            #pragma unroll
            for (int r = 0; r < 4; ++r)
                out[(size_t)(gm + r) * N_DIM + gn] = v[r] * sc + bi;
        }
    }
#undef GLDS
#undef STG_A
#undef STG_B
#undef BAR
#undef LGKM0
#undef VMC
}

// ---------------- fallback: fused dequant GEMM (R1 kernel, known-good) ----------------
__device__ __forceinline__ int swz(int row, int kbyte) {
    return row * 128 + (kbyte ^ ((row & 7) << 4));
}

__global__ __launch_bounds__(256, 2)
void qlin_kernel(const float* __restrict__ x,
                 const int*   __restrict__ wq,
                 const float* __restrict__ scale,
                 const float* __restrict__ bias,
                 float* __restrict__ out)
{
    __shared__ short As[128 * 64];
    __shared__ short Bs[128 * 64];

    const int t  = threadIdx.x;
    const int n0 = blockIdx.x * 128;
    const int m0 = blockIdx.y * 128;

    const int sr = t >> 1;
    const int sh = t & 1;

    const float* ag = x  + (size_t)(m0 + sr) * K_DIM + sh * 32;
    const int*   bg = wq + (size_t)(n0 + sr) * KP    + sh * 16;

    const int lane = t & 63;
    const int wv   = t >> 6;
    const int wm   = wv >> 1;
    const int wn   = wv & 1;
    const int lr   = lane & 15;
    const int lk   = lane >> 4;

    f32x4 acc[4][4];
    #pragma unroll
    for (int i = 0; i < 4; ++i)
        #pragma unroll
        for (int j = 0; j < 4; ++j)
            acc[i][j] = (f32x4){0.f, 0.f, 0.f, 0.f};

    f32x4 ar[8];
    i32x4 br[4];

    #pragma unroll
    for (int i = 0; i < 8; ++i) ar[i] = *(const f32x4*)(ag + i * 4);
    #pragma unroll
    for (int i = 0; i < 4; ++i) br[i] = *(const i32x4*)(bg + i * 4);

    for (int kt = 0; kt < 64; ++kt) {
        #pragma unroll
        for (int c = 0; c < 4; ++c) {
            bf16x8 pa;
            #pragma unroll
            for (int j = 0; j < 8; ++j)
                pa[j] = f2bf(ar[c * 2 + (j >> 2)][j & 3]);
            *(bf16x8*)((char*)As + swz(sr, sh * 64 + c * 16)) = pa;

            bf16x8 pb;
            #pragma unroll
            for (int j = 0; j < 4; ++j) {
                const int q = br[c][j] ^ 0x88;
                const float flo = __builtin_bit_cast(float, 0x4B000000 | (q & 15))        - 8388616.0f;
                const float fhi = __builtin_bit_cast(float, 0x4B000000 | ((q >> 4) & 15)) - 8388616.0f;
                pb[2 * j]     = f2bf(flo);
                pb[2 * j + 1] = f2bf(fhi);
            }
            *(bf16x8*)((char*)Bs + swz(sr, sh * 64 + c * 16)) = pb;
        }
        __syncthreads();

        if (kt + 1 < 64) {
            const float* an = ag + (kt + 1) * 64;
            const int*   bn = bg + (kt + 1) * 32;
            #pragma unroll
            for (int i = 0; i < 8; ++i) ar[i] = *(const f32x4*)(an + i * 4);
            #pragma unroll
            for (int i = 0; i < 4; ++i) br[i] = *(const i32x4*)(bn + i * 4);
        }

        #pragma unroll
        for (int ks = 0; ks < 2; ++ks) {
            const int kb = ks * 64 + lk * 16;
            bf16x8 af2[4], bf2[4];
            #pragma unroll
            for (int mi = 0; mi < 4; ++mi)
                af2[mi] = *(const bf16x8*)((const char*)As + swz(wm * 64 + mi * 16 + lr, kb));
            #pragma unroll
            for (int ni = 0; ni < 4; ++ni)
                bf2[ni] = *(const bf16x8*)((const char*)Bs + swz(wn * 64 + ni * 16 + lr, kb));
            #pragma unroll
            for (int mi = 0; mi < 4; ++mi)
                #pragma unroll
                for (int ni = 0; ni < 4; ++ni)
                    acc[mi][ni] = __builtin_amdgcn_mfma_f32_16x16x32_bf16(
                        af2[mi], bf2[ni], acc[mi][ni], 0, 0, 0);
        }
        __syncthreads();
    }

    #pragma unroll
    for (int ni = 0; ni < 4; ++ni) {
        const int gn = n0 + wn * 64 + ni * 16 + lr;
        const float sc = scale[gn];
        const float bi = bias[gn];
        #pragma unroll
        for (int mi = 0; mi < 4; ++mi) {
            const int gm = m0 + wm * 64 + mi * 16 + lk * 4;
            const f32x4 v = acc[mi][ni];
            #pragma unroll
            for (int r2 = 0; r2 < 4; ++r2)
                out[(size_t)(gm + r2) * N_DIM + gn] = v[r2] * sc + bi;
        }
    }
}

extern "C" void kernel_launch(void* const* d_in, const int* in_sizes, int n_in,
                              void* d_out, int out_size, void* d_ws, size_t ws_size,
                              hipStream_t stream)
{
    const float* x     = (const float*)d_in[0];
    const int*   wq    = (const int*)d_in[1];
    const float* scale = (const float*)d_in[2];
    const float* bias  = (const float*)d_in[3];
    float*       out   = (float*)d_out;

    if (ws_size >= WS_NEED) {
        short* xb = (short*)d_ws;
        short* wb = (short*)((char*)d_ws + A_WS_BYTES);
        cvt_x_kernel<<<16384, 256, 0, stream>>>(x, xb);
        dequant_w_kernel<<<22016, 256, 0, stream>>>(wq, wb);
        const int nwg = (N_DIM / BN) * (M_DIM / BM);   // 43*32 = 1376
        gemm256_kernel<<<nwg, 512, 0, stream>>>(xb, wb, scale, bias, out);
    } else {
        qlin_kernel<<<dim3(N_DIM / 128, M_DIM / 128), 256, 0, stream>>>(x, wq, scale, bias, out);
    }
}

// Round 10
// 729.639 us; speedup vs baseline: 1.3340x; 1.1529x over previous
//
#include <hip/hip_runtime.h>
#include <hip/hip_bf16.h>

typedef __attribute__((ext_vector_type(4))) float  f32x4;
typedef __attribute__((ext_vector_type(8))) short  bf16x8;
typedef __attribute__((ext_vector_type(4))) int    i32x4;

#define M_DIM 8192
#define N_DIM 11008
#define K_DIM 4096
#define KP    2048

#define A_WS_BYTES ((size_t)M_DIM * K_DIM * 2)
#define B_WS_BYTES ((size_t)N_DIM * K_DIM * 2)
#define WS_NEED    (A_WS_BYTES + B_WS_BYTES)

// ---- 256x256 tile, BK=64, 8 waves (2Mx4N), 2 LDS buffers, 8-phase schedule ----
#define BM 256
#define BN 256
#define BK 64
#define NT  (K_DIM / BK)     // 64 K-tiles
#define NIT (NT / 2)         // 32 iterations (2 tiles/iter)
#define HALF_BYTES 16384     // 128 rows x 64 cols x 2B
#define ABUF_BYTES 32768     // A region per buffer (2 halves)
#define BUF_BYTES  65536     // A + B per buffer
// LDS total: 2 * 65536 = 131072

__device__ __forceinline__ short f2bf(float f) {
    return __builtin_bit_cast(short, __float2bfloat16(f));
}

// ---------------- prepass: x fp32 -> bf16 ----------------
__global__ __launch_bounds__(256)
void cvt_x_kernel(const float* __restrict__ x, short* __restrict__ xb)
{
    const size_t i = ((size_t)blockIdx.x * 256 + threadIdx.x) * 8;
    const f32x4 a = *(const f32x4*)(x + i);
    const f32x4 b = *(const f32x4*)(x + i + 4);
    bf16x8 o;
    #pragma unroll
    for (int j = 0; j < 4; ++j) {
        o[j]     = f2bf(a[j]);
        o[4 + j] = f2bf(b[j]);
    }
    *(bf16x8*)(xb + i) = o;
}

// ---------------- prepass: packed int4 -> bf16 ----------------
__global__ __launch_bounds__(256)
void dequant_w_kernel(const int* __restrict__ wq, short* __restrict__ wb)
{
    const size_t i = ((size_t)blockIdx.x * 256 + threadIdx.x) * 4;
    const i32x4 v = *(const i32x4*)(wq + i);
    bf16x8 o;
    #pragma unroll
    for (int j = 0; j < 4; ++j) {
        const int q = (v[j] & 0xFF) ^ 0x88;
        o[2 * j]     = f2bf((float)((q & 15) - 8));
        o[2 * j + 1] = f2bf((float)(((q >> 4) & 15) - 8));
    }
    *(bf16x8*)(wb + i * 2) = o;
}

// ---------------- main GEMM: 8-phase m201-template port (R5, verified best) ----------------
__global__ __launch_bounds__(512, 2)
void gemm256_kernel(const short* __restrict__ A,     // [8192][4096] bf16
                    const short* __restrict__ Bw,    // [11008][4096] bf16
                    const float* __restrict__ scale,
                    const float* __restrict__ bias,
                    float* __restrict__ out)
{
    __shared__ char lds[2 * BUF_BYTES];   // 128 KiB

    const int t    = threadIdx.x;
    const int lane = t & 63;
    const int wv   = t >> 6;          // 0..7
    const int wm   = wv >> 2;         // 0..1 -> M half (128 rows)
    const int wn   = wv & 3;          // 0..3 -> N quarter (64 rows)

    // bijective XCD chunk swizzle (nwg = 1376, %8 == 0)
    const int nbx = N_DIM / BN;                       // 43
    const int cpx = (nbx * (M_DIM / BM)) >> 3;        // 172
    const int bid = blockIdx.x;
    const int sid = (bid & 7) * cpx + (bid >> 3);
    const int by  = sid / nbx;
    const int bx  = sid - by * nbx;
    const int m0  = by * BM;
    const int n0  = bx * BN;

    // ---- staging geometry: thread t covers row (t>>3)+{0,64}+h*128, granule t&7 ----
    // LDS phys (row, g) holds logical (row, g ^ (row&7)); source pre-swizzled (rule #21).
    const int srow = t >> 3;                               // 0..63
    const int scol = ((t & 7) ^ (srow & 7)) * 8;           // element offset in row
    const short* aS = A  + (size_t)(m0 + srow) * K_DIM + scol;
    const short* bS = Bw + (size_t)(n0 + srow) * K_DIM + scol;

#define STG(SRC, MOFF, BUFI, H, KOFF) do {                                                  \
    _Pragma("unroll")                                                                       \
    for (int i_ = 0; i_ < 2; ++i_)                                                          \
        __builtin_amdgcn_global_load_lds(                                                   \
            (const __attribute__((address_space(1))) unsigned int*)                         \
                ((SRC) + ((H) * 128 + i_ * 64) * (size_t)K_DIM + (KOFF)),                   \
            (__attribute__((address_space(3))) unsigned int*)                               \
                (lds + (BUFI) * BUF_BYTES + (MOFF) + (H) * HALF_BYTES + i_ * 8192 + t * 16),\
            16, 0, 0);                                                                      \
} while (0)

    // ---- fragment read offsets (within a buffer); ks1 = offset ^ 64 ----
    const int lr = lane & 15;
    const int lk = lane >> 4;
    int aOff[8], bOff[4];
    #pragma unroll
    for (int mi = 0; mi < 8; ++mi) {
        const int row = wm * 128 + mi * 16 + lr;
        aOff[mi] = row * 128 + ((lk ^ (row & 7)) * 16);
    }
    #pragma unroll
    for (int ni = 0; ni < 4; ++ni) {
        const int row = wn * 64 + ni * 16 + lr;
        bOff[ni] = ABUF_BYTES + row * 128 + ((lk ^ (row & 7)) * 16);
    }

    f32x4 acc[8][4];
    #pragma unroll
    for (int mi = 0; mi < 8; ++mi)
        #pragma unroll
        for (int ni = 0; ni < 4; ++ni)
            acc[mi][ni] = (f32x4){0.f, 0.f, 0.f, 0.f};

    bf16x8 af[4][2], bf[4][2];

#define RDA(BUFP, MIBASE) do {                                                   \
    _Pragma("unroll")                                                            \
    for (int m_ = 0; m_ < 4; ++m_) {                                             \
        af[m_][0] = *(const bf16x8*)((BUFP) + aOff[(MIBASE) + m_]);              \
        af[m_][1] = *(const bf16x8*)((BUFP) + (aOff[(MIBASE) + m_] ^ 64));       \
    }                                                                            \
} while (0)

#define RDB(BUFP, NIBASE) do {                                                   \
    _Pragma("unroll")                                                            \
    for (int n_ = 0; n_ < 2; ++n_) {                                             \
        bf[(NIBASE) + n_][0] = *(const bf16x8*)((BUFP) + bOff[(NIBASE) + n_]);   \
        bf[(NIBASE) + n_][1] = *(const bf16x8*)((BUFP) + (bOff[(NIBASE) + n_] ^ 64)); \
    }                                                                            \
} while (0)

#define MFMAQ(ACCMI, NIBASE) do {                                                \
    __builtin_amdgcn_s_setprio(1);                                               \
    _Pragma("unroll")                                                            \
    for (int m_ = 0; m_ < 4; ++m_)                                               \
        _Pragma("unroll")                                                        \
        for (int n_ = 0; n_ < 2; ++n_) {                                         \
            acc[(ACCMI) + m_][(NIBASE) + n_] = __builtin_amdgcn_mfma_f32_16x16x32_bf16( \
                af[m_][0], bf[(NIBASE) + n_][0], acc[(ACCMI) + m_][(NIBASE) + n_], 0, 0, 0); \
            acc[(ACCMI) + m_][(NIBASE) + n_] = __builtin_amdgcn_mfma_f32_16x16x32_bf16( \
                af[m_][1], bf[(NIBASE) + n_][1], acc[(ACCMI) + m_][(NIBASE) + n_], 0, 0, 0); \
        }                                                                        \
    __builtin_amdgcn_s_setprio(0);                                               \
} while (0)

#define BAR   __builtin_amdgcn_s_barrier()
#define LGKM0 asm volatile("s_waitcnt lgkmcnt(0)" ::: "memory")
#define VMC(N) asm volatile("s_waitcnt vmcnt(" #N ")" ::: "memory")

    // ---- prologue: emulate iter -1 stage slots ----
    // tile0 -> buf0 (B-h0, B-h1, A-h0, A-h1); tile1 B -> buf1 (B-h0, B-h1)
    STG(bS, ABUF_BYTES, 0, 0, 0);
    STG(bS, ABUF_BYTES, 0, 1, 0);
    STG(aS, 0,          0, 0, 0);
    STG(aS, 0,          0, 1, 0);
    STG(bS, ABUF_BYTES, 1, 0, BK);
    STG(bS, ABUF_BYTES, 1, 1, BK);
    VMC(4);                       // drain tile0 (8 oldest loads); tile1-B may fly
    BAR;

    const char* b0p = lds;
    const char* b1p = lds + BUF_BYTES;

    for (int it = 0; it < NIT; ++it) {
        const int kc1 = (2 * it + 1) * BK;   // buf1 tile (this iter)
        const int kn0 = (2 * it + 2) * BK;   // next buf0 tile
        const int kn1 = (2 * it + 3) * BK;   // next buf1 tile
        const bool nl = (it + 1 < NIT);

        // ---- P1: Q00 of tile 2i (buf0) ----
        RDA(b0p, 0); RDB(b0p, 0);
        STG(aS, 0, 1, 0, kc1);               // tile 2i+1 A-h0 (buf1-A freed prev P7)
        BAR; LGKM0; MFMAQ(0, 0); BAR;
        // ---- P2: Q01 ----
        RDB(b0p, 2);
        STG(aS, 0, 1, 1, kc1);               // tile 2i+1 A-h1
        BAR; LGKM0; MFMAQ(0, 2); BAR;
        // ---- P3: Q11 ----
        RDA(b0p, 4);
        if (nl) STG(bS, ABUF_BYTES, 0, 0, kn0);  // tile 2i+2 B-h0 (buf0-B freed after P2)
        BAR; LGKM0; MFMAQ(4, 2); BAR;
        // ---- P4: Q10 (no reads; bf[0-1], af[4-7] live) ----
        if (nl) STG(bS, ABUF_BYTES, 0, 1, kn0);  // tile 2i+2 B-h1
        BAR; MFMAQ(4, 0);
        if (nl) VMC(4); else VMC(0);         // drain tile 2i+1 A (P1,P2 stages)
        BAR;

        // ---- P5: Q00 of tile 2i+1 (buf1) ----
        RDA(b1p, 0); RDB(b1p, 0);
        if (nl) STG(aS, 0, 0, 0, kn0);       // tile 2i+2 A-h0 (buf0-A freed after P3)
        BAR; LGKM0; MFMAQ(0, 0); BAR;
        // ---- P6: Q01 ----
        RDB(b1p, 2);
        if (nl) STG(aS, 0, 0, 1, kn0);       // tile 2i+2 A-h1
        BAR; LGKM0; MFMAQ(0, 2); BAR;
        // ---- P7: Q11 ----
        RDA(b1p, 4);
        if (nl) STG(bS, ABUF_BYTES, 1, 0, kn1);  // tile 2i+3 B-h0 (buf1-B freed after P6)
        BAR; LGKM0; MFMAQ(4, 2); BAR;
        // ---- P8: Q10 ----
        if (nl) STG(bS, ABUF_BYTES, 1, 1, kn1);  // tile 2i+3 B-h1
        BAR; MFMAQ(4, 0);
        VMC(4);                               // drain tile 2i+2 (B at P3/P4, A at P5/P6)
        if (nl) BAR;
    }

    // ---- epilogue: out = acc * scale[n] + bias[n] ----
    // C/D layout: col = lane&15, row = (lane>>4)*4 + reg   (verified, passing R1-R9)
    #pragma unroll
    for (int ni = 0; ni < 4; ++ni) {
        const int gn = n0 + wn * 64 + ni * 16 + lr;
        const float sc = scale[gn];
        const float bi = bias[gn];
        #pragma unroll
        for (int mi = 0; mi < 8; ++mi) {
            const int gm = m0 + wm * 128 + mi * 16 + lk * 4;
            const f32x4 v = acc[mi][ni];
            #pragma unroll
            for (int r = 0; r < 4; ++r)
                out[(size_t)(gm + r) * N_DIM + gn] = v[r] * sc + bi;
        }
    }
#undef STG
#undef RDA
#undef RDB
#undef MFMAQ
#undef BAR
#undef LGKM0
#undef VMC
}

// ---------------- fallback: fused dequant GEMM (R1 kernel, known-good) ----------------
__device__ __forceinline__ int swz(int row, int kbyte) {
    return row * 128 + (kbyte ^ ((row & 7) << 4));
}

__global__ __launch_bounds__(256, 2)
void qlin_kernel(const float* __restrict__ x,
                 const int*   __restrict__ wq,
                 const float* __restrict__ scale,
                 const float* __restrict__ bias,
                 float* __restrict__ out)
{
    __shared__ short As[128 * 64];
    __shared__ short Bs[128 * 64];

    const int t  = threadIdx.x;
    const int n0 = blockIdx.x * 128;
    const int m0 = blockIdx.y * 128;

    const int sr = t >> 1;
    const int sh = t & 1;

    const float* ag = x  + (size_t)(m0 + sr) * K_DIM + sh * 32;
    const int*   bg = wq + (size_t)(n0 + sr) * KP    + sh * 16;

    const int lane = t & 63;
    const int wv   = t >> 6;
    const int wm   = wv >> 1;
    const int wn   = wv & 1;
    const int lr   = lane & 15;
    const int lk   = lane >> 4;

    f32x4 acc[4][4];
    #pragma unroll
    for (int i = 0; i < 4; ++i)
        #pragma unroll
        for (int j = 0; j < 4; ++j)
            acc[i][j] = (f32x4){0.f, 0.f, 0.f, 0.f};

    f32x4 ar[8];
    i32x4 br[4];

    #pragma unroll
    for (int i = 0; i < 8; ++i) ar[i] = *(const f32x4*)(ag + i * 4);
    #pragma unroll
    for (int i = 0; i < 4; ++i) br[i] = *(const i32x4*)(bg + i * 4);

    for (int kt = 0; kt < 64; ++kt) {
        #pragma unroll
        for (int c = 0; c < 4; ++c) {
            bf16x8 pa;
            #pragma unroll
            for (int j = 0; j < 8; ++j)
                pa[j] = f2bf(ar[c * 2 + (j >> 2)][j & 3]);
            *(bf16x8*)((char*)As + swz(sr, sh * 64 + c * 16)) = pa;

            bf16x8 pb;
            #pragma unroll
            for (int j = 0; j < 4; ++j) {
                const int q = br[c][j] ^ 0x88;
                const float flo = __builtin_bit_cast(float, 0x4B000000 | (q & 15))        - 8388616.0f;
                const float fhi = __builtin_bit_cast(float, 0x4B000000 | ((q >> 4) & 15)) - 8388616.0f;
                pb[2 * j]     = f2bf(flo);
                pb[2 * j + 1] = f2bf(fhi);
            }
            *(bf16x8*)((char*)Bs + swz(sr, sh * 64 + c * 16)) = pb;
        }
        __syncthreads();

        if (kt + 1 < 64) {
            const float* an = ag + (kt + 1) * 64;
            const int*   bn = bg + (kt + 1) * 32;
            #pragma unroll
            for (int i = 0; i < 8; ++i) ar[i] = *(const f32x4*)(an + i * 4);
            #pragma unroll
            for (int i = 0; i < 4; ++i) br[i] = *(const i32x4*)(bn + i * 4);
        }

        #pragma unroll
        for (int ks = 0; ks < 2; ++ks) {
            const int kb = ks * 64 + lk * 16;
            bf16x8 af2[4], bf2[4];
            #pragma unroll
            for (int mi = 0; mi < 4; ++mi)
                af2[mi] = *(const bf16x8*)((const char*)As + swz(wm * 64 + mi * 16 + lr, kb));
            #pragma unroll
            for (int ni = 0; ni < 4; ++ni)
                bf2[ni] = *(const bf16x8*)((const char*)Bs + swz(wn * 64 + ni * 16 + lr, kb));
            #pragma unroll
            for (int mi = 0; mi < 4; ++mi)
                #pragma unroll
                for (int ni = 0; ni < 4; ++ni)
                    acc[mi][ni] = __builtin_amdgcn_mfma_f32_16x16x32_bf16(
                        af2[mi], bf2[ni], acc[mi][ni], 0, 0, 0);
        }
        __syncthreads();
    }

    #pragma unroll
    for (int ni = 0; ni < 4; ++ni) {
        const int gn = n0 + wn * 64 + ni * 16 + lr;
        const float sc = scale[gn];
        const float bi = bias[gn];
        #pragma unroll
        for (int mi = 0; mi < 4; ++mi) {
            const int gm = m0 + wm * 64 + mi * 16 + lk * 4;
            const f32x4 v = acc[mi][ni];
            #pragma unroll
            for (int r2 = 0; r2 < 4; ++r2)
                out[(size_t)(gm + r2) * N_DIM + gn] = v[r2] * sc + bi;
        }
    }
}

extern "C" void kernel_launch(void* const* d_in, const int* in_sizes, int n_in,
                              void* d_out, int out_size, void* d_ws, size_t ws_size,
                              hipStream_t stream)
{
    const float* x     = (const float*)d_in[0];
    const int*   wq    = (const int*)d_in[1];
    const float* scale = (const float*)d_in[2];
    const float* bias  = (const float*)d_in[3];
    float*       out   = (float*)d_out;

    if (ws_size >= WS_NEED) {
        short* xb = (short*)d_ws;
        short* wb = (short*)((char*)d_ws + A_WS_BYTES);
        cvt_x_kernel<<<16384, 256, 0, stream>>>(x, xb);
        dequant_w_kernel<<<22016, 256, 0, stream>>>(wq, wb);
        const int nwg = (N_DIM / BN) * (M_DIM / BM);   // 43*32 = 1376
        gemm256_kernel<<<nwg, 512, 0, stream>>>(xb, wb, scale, bias, out);
    } else {
        qlin_kernel<<<dim3(N_DIM / 128, M_DIM / 128), 256, 0, stream>>>(x, wq, scale, bias, out);
    }
}